// Round 1
// baseline (2589.258 us; speedup 1.0000x reference)
//
#include <hip/hip_runtime.h>
#include <math.h>

#define BB 4
#define CC 256
#define NHEAD 4
#define DH 32
#define NN 4096
#define HID 128
#define SCALE_F 10.0f

// ---------------- kernel 1: qkv projection ----------------
// qkv[b][o][i] = sum_c w[o][c] * x[b][c][i]
// o in [0,128) -> q[(b*128+o)*N + i]
// o in [128,256) -> k[(b*128+o-128)*N + i]
// o in [256,384) -> vt[((b*4+h)*N + i)*32 + d]   (transposed for PV phase)
__global__ __launch_bounds__(256) void qkv_proj(const float* __restrict__ x,
                                                const float* __restrict__ w,
                                                float* __restrict__ q,
                                                float* __restrict__ k,
                                                float* __restrict__ vt) {
    int i = blockIdx.x * 256 + threadIdx.x;
    int o0 = blockIdx.y * 8;
    int b = blockIdx.z;
    const float* xb = x + (size_t)b * CC * NN;
    float acc[8];
#pragma unroll
    for (int oo = 0; oo < 8; oo++) acc[oo] = 0.f;
    for (int c = 0; c < CC; c++) {
        float xv = xb[(size_t)c * NN + i];
#pragma unroll
        for (int oo = 0; oo < 8; oo++)
            acc[oo] = fmaf(w[(o0 + oo) * CC + c], xv, acc[oo]);
    }
#pragma unroll
    for (int oo = 0; oo < 8; oo++) {
        int o = o0 + oo;
        if (o < 128) {
            q[((size_t)b * 128 + o) * NN + i] = acc[oo];
        } else if (o < 256) {
            k[((size_t)b * 128 + (o - 128)) * NN + i] = acc[oo];
        } else {
            int o2 = o - 256;
            int h = o2 >> 5, d = o2 & 31;
            vt[(((size_t)(b * 4 + h)) * NN + i) * 32 + d] = acc[oo];
        }
    }
}

// ---------------- kernel 2: l2 normalize q,k columns over d ----------------
__global__ __launch_bounds__(256) void l2norm_cols(float* __restrict__ q,
                                                   float* __restrict__ k) {
    int i = blockIdx.x * 256 + threadIdx.x;
    int bh = blockIdx.y;
    float* p = (blockIdx.z == 0) ? q : k;
    float v[32];
    float ss = 0.f;
#pragma unroll
    for (int d = 0; d < 32; d++) {
        v[d] = p[((size_t)bh * 32 + d) * NN + i];
        ss = fmaf(v[d], v[d], ss);
    }
    float nrm = sqrtf(ss);
    float inv = 1.f / fmaxf(nrm, 1e-12f);
#pragma unroll
    for (int d = 0; d < 32; d++)
        p[((size_t)bh * 32 + d) * NN + i] = v[d] * inv;
}

// ---------------- kernel 3: attention (online softmax, chunked) ----------------
// One block: 8 query rows of one (b,h). 4 chunks of 1024 keys.
#define TQ 8
#define JC 1024
#define SROW 260  // padded segment stride (256 data + 4 pad) to kill bank conflicts

__global__ __launch_bounds__(256) void attn(const float* __restrict__ q,
                                            const float* __restrict__ k,
                                            const float* __restrict__ vt,
                                            float* __restrict__ att) {
    __shared__ float qsT[32][8];       // [d][r], pre-scaled by 10
    __shared__ float sbuf[32 * SROW];  // [(r*4+seg)*SROW + jj]
    __shared__ float m_run[8], l_run[8], alpha_s[8], rowsum[8];
    __shared__ float wavemax[4][8];
    __shared__ float4 red[256];

    int t = threadIdx.x;
    int bh = blockIdx.y;
    int i0 = blockIdx.x * TQ;
    int wave = t >> 6;

    {
        int r = t >> 5, d = t & 31;
        qsT[d][r] = q[((size_t)bh * 32 + d) * NN + i0 + r] * SCALE_F;
    }
    if (t < 8) { m_run[t] = -INFINITY; l_run[t] = 0.f; }

    float4 acc = make_float4(0.f, 0.f, 0.f, 0.f);
    int rB = t >> 5;          // row owned in exp/phase-B
    int wB = t & 31;
    int sB = wB >> 3;         // chunk quarter
    int d4 = wB & 7;          // float4 group of d
    __syncthreads();

    const float* kb = k + (size_t)bh * 32 * NN;
    const float4* vb = (const float4*)(vt + (size_t)bh * NN * 32);

    for (int j0 = 0; j0 < NN; j0 += JC) {
        // ---- phase A: s = (10*qhat) . khat for 8 rows ----
        float lmax[8];
#pragma unroll
        for (int r = 0; r < 8; r++) lmax[r] = -INFINITY;
        for (int jj4 = 0; jj4 < 4; jj4++) {
            int jl = t + 256 * jj4;
            int j = j0 + jl;
            float sr[8];
#pragma unroll
            for (int r = 0; r < 8; r++) sr[r] = 0.f;
            for (int dd = 0; dd < 32; dd++) {
                float kv = kb[(size_t)dd * NN + j];
                float4 qa = *(const float4*)&qsT[dd][0];
                float4 qb = *(const float4*)&qsT[dd][4];
                sr[0] = fmaf(qa.x, kv, sr[0]);
                sr[1] = fmaf(qa.y, kv, sr[1]);
                sr[2] = fmaf(qa.z, kv, sr[2]);
                sr[3] = fmaf(qa.w, kv, sr[3]);
                sr[4] = fmaf(qb.x, kv, sr[4]);
                sr[5] = fmaf(qb.y, kv, sr[5]);
                sr[6] = fmaf(qb.z, kv, sr[6]);
                sr[7] = fmaf(qb.w, kv, sr[7]);
            }
            int seg = jl >> 8, jjj = jl & 255;
#pragma unroll
            for (int r = 0; r < 8; r++) {
                sbuf[(r * 4 + seg) * SROW + jjj] = sr[r];
                lmax[r] = fmaxf(lmax[r], sr[r]);
            }
        }
#pragma unroll
        for (int r = 0; r < 8; r++) {
#pragma unroll
            for (int off = 32; off >= 1; off >>= 1)
                lmax[r] = fmaxf(lmax[r], __shfl_xor(lmax[r], off));
        }
        if ((t & 63) == 0) {
#pragma unroll
            for (int r = 0; r < 8; r++) wavemax[wave][r] = lmax[r];
        }
        __syncthreads();
        if (t < 8) {
            float mc = fmaxf(fmaxf(wavemax[0][t], wavemax[1][t]),
                             fmaxf(wavemax[2][t], wavemax[3][t]));
            float mnew = fmaxf(m_run[t], mc);
            alpha_s[t] = __expf(m_run[t] - mnew);
            m_run[t] = mnew;
        }
        __syncthreads();
        // ---- exp pass: p = exp(s - m), row sums ----
        {
            float m = m_run[rB];
            float lsum = 0.f;
#pragma unroll
            for (int ii = 0; ii < 32; ii++) {
                int jl = wB + 32 * ii;
                int idx = (rB * 4 + (jl >> 8)) * SROW + (jl & 255);
                float pv = __expf(sbuf[idx] - m);
                sbuf[idx] = pv;
                lsum += pv;
            }
#pragma unroll
            for (int off = 16; off >= 1; off >>= 1) lsum += __shfl_xor(lsum, off);
            if (wB == 0) rowsum[rB] = lsum;
        }
        __syncthreads();
        if (t < 8) l_run[t] = l_run[t] * alpha_s[t] + rowsum[t];
        // ---- phase B: acc = alpha*acc + sum_j p[rB][j] * v[j][d4*4..+3] ----
        {
            float a = alpha_s[rB];
            acc.x *= a; acc.y *= a; acc.z *= a; acc.w *= a;
            const float4* vrow = vb + ((size_t)(j0 + sB * 256)) * 8 + d4;
            const float* prow = &sbuf[(rB * 4 + sB) * SROW];
            for (int jj = 0; jj < 256; jj++) {
                float pv = prow[jj];
                float4 vv = vrow[(size_t)jj * 8];
                acc.x = fmaf(pv, vv.x, acc.x);
                acc.y = fmaf(pv, vv.y, acc.y);
                acc.z = fmaf(pv, vv.z, acc.z);
                acc.w = fmaf(pv, vv.w, acc.w);
            }
        }
        __syncthreads();
    }
    // ---- final: reduce quarters, divide by l, write att[b][h*32+d][i] ----
    red[t] = acc;
    __syncthreads();
    if (t < 64) {
        int r = t >> 3, g = t & 7;
        float4 o0 = red[r * 32 + 0 * 8 + g];
        float4 o1 = red[r * 32 + 1 * 8 + g];
        float4 o2 = red[r * 32 + 2 * 8 + g];
        float4 o3 = red[r * 32 + 3 * 8 + g];
        float inv = 1.f / l_run[r];
        float vx = (o0.x + o1.x + o2.x + o3.x) * inv;
        float vy = (o0.y + o1.y + o2.y + o3.y) * inv;
        float vz = (o0.z + o1.z + o2.z + o3.z) * inv;
        float vw = (o0.w + o1.w + o2.w + o3.w) * inv;
        size_t base = ((size_t)bh * 32 + g * 4) * NN + i0 + r;
        att[base + 0 * NN] = vx;
        att[base + 1 * NN] = vy;
        att[base + 2 * NN] = vz;
        att[base + 3 * NN] = vw;
    }
}

// ---------------- kernel 4: output projection + bias ----------------
__global__ __launch_bounds__(256) void out_proj(const float* __restrict__ att,
                                                const float* __restrict__ wo,
                                                const float* __restrict__ bo,
                                                float* __restrict__ out) {
    int i = blockIdx.x * 256 + threadIdx.x;
    int o0 = blockIdx.y * 8;
    int b = blockIdx.z;
    const float* ab = att + (size_t)b * HID * NN;
    float acc[8];
#pragma unroll
    for (int oo = 0; oo < 8; oo++) acc[oo] = 0.f;
    for (int c = 0; c < HID; c++) {
        float av = ab[(size_t)c * NN + i];
#pragma unroll
        for (int oo = 0; oo < 8; oo++)
            acc[oo] = fmaf(wo[(o0 + oo) * HID + c], av, acc[oo]);
    }
#pragma unroll
    for (int oo = 0; oo < 8; oo++)
        out[((size_t)b * CC + o0 + oo) * NN + i] = acc[oo] + bo[o0 + oo];
}

extern "C" void kernel_launch(void* const* d_in, const int* in_sizes, int n_in,
                              void* d_out, int out_size, void* d_ws, size_t ws_size,
                              hipStream_t stream) {
    const float* x     = (const float*)d_in[0];
    const float* w_qkv = (const float*)d_in[1];
    const float* w_out = (const float*)d_in[2];
    const float* b_out = (const float*)d_in[3];
    float* out = (float*)d_out;

    const size_t SEG = (size_t)BB * HID * NN;  // 2,097,152 floats = 8 MB
    float* q   = (float*)d_ws;
    float* k   = q + SEG;
    float* vt  = k + SEG;
    float* att = vt + SEG;

    qkv_proj<<<dim3(NN / 256, 384 / 8, BB), 256, 0, stream>>>(x, w_qkv, q, k, vt);
    l2norm_cols<<<dim3(NN / 256, BB * NHEAD, 2), 256, 0, stream>>>(q, k);
    attn<<<dim3(NN / TQ, BB * NHEAD, 1), 256, 0, stream>>>(q, k, vt, att);
    out_proj<<<dim3(NN / 256, CC / 8, BB), 256, 0, stream>>>(att, w_out, b_out, out);
}

// Round 2
// 701.845 us; speedup vs baseline: 3.6892x; 3.6892x over previous
//
#include <hip/hip_runtime.h>
#include <math.h>

#define BB 4
#define CC 256
#define NHEAD 4
#define DH 32
#define NN 4096
#define HID 128

typedef _Float16 f16;
typedef _Float16 f16x8 __attribute__((ext_vector_type(8)));
typedef float f32x4 __attribute__((ext_vector_type(4)));

#define QPRESCALE 10.0f   // fold scale into q-hat
#define EXPSHIFT 10.0f    // static softmax shift: s<=10 always (|q̂·k̂|<=1)

// ---------------- kernel 1: qkv projection ----------------
// q32,k32: fp32, d-major [b*128+o][i].  V: straight to f16 d-major [bh*32+d][i].
__global__ __launch_bounds__(256) void qkv_proj(const float* __restrict__ x,
                                                const float* __restrict__ w,
                                                float* __restrict__ q32,
                                                float* __restrict__ k32,
                                                f16* __restrict__ vh) {
    int i = blockIdx.x * 256 + threadIdx.x;
    int o0 = blockIdx.y * 8;
    int b = blockIdx.z;
    const float* xb = x + (size_t)b * CC * NN;
    float acc[8];
#pragma unroll
    for (int oo = 0; oo < 8; oo++) acc[oo] = 0.f;
    for (int c = 0; c < CC; c++) {
        float xv = xb[(size_t)c * NN + i];
#pragma unroll
        for (int oo = 0; oo < 8; oo++)
            acc[oo] = fmaf(w[(o0 + oo) * CC + c], xv, acc[oo]);
    }
#pragma unroll
    for (int oo = 0; oo < 8; oo++) {
        int o = o0 + oo;
        if (o < 128) {
            q32[((size_t)b * 128 + o) * NN + i] = acc[oo];
        } else if (o < 256) {
            k32[((size_t)b * 128 + (o - 128)) * NN + i] = acc[oo];
        } else {
            vh[((size_t)b * 128 + (o - 256)) * NN + i] = (f16)acc[oo];
        }
    }
}

// ---------------- kernel 2: l2 normalize + f16 transpose to i-major ----------
// reads fp32 d-major, writes f16 [bh][i][32] (q prescaled by 10).
__global__ __launch_bounds__(256) void l2norm_cvt(const float* __restrict__ q32,
                                                  const float* __restrict__ k32,
                                                  f16* __restrict__ qh,
                                                  f16* __restrict__ kh) {
    int i = blockIdx.x * 256 + threadIdx.x;
    int bh = blockIdx.y;
    const float* src = (blockIdx.z == 0) ? q32 : k32;
    f16* dst = (blockIdx.z == 0) ? qh : kh;
    float extra = (blockIdx.z == 0) ? QPRESCALE : 1.0f;
    float v[32];
    float ss = 0.f;
#pragma unroll
    for (int d = 0; d < 32; d++) {
        v[d] = src[((size_t)bh * 32 + d) * NN + i];
        ss = fmaf(v[d], v[d], ss);
    }
    float inv = extra / fmaxf(sqrtf(ss), 1e-12f);
    f16x8 o[4];
#pragma unroll
    for (int g = 0; g < 4; g++)
#pragma unroll
        for (int e = 0; e < 8; e++) o[g][e] = (f16)(v[g * 8 + e] * inv);
    f16x8* dp = (f16x8*)(dst + ((size_t)bh * NN + i) * 32);
#pragma unroll
    for (int g = 0; g < 4; g++) dp[g] = o[g];
}

// ---------------- kernel 3: MFMA flash attention ----------------
// Block = 4 independent waves; wave handles 32 q-rows; K-tiles of 64.
// Static softmax shift (s<=10): no online max, no in-loop cross-lane reductions.
__global__ __launch_bounds__(256) void attn_mfma(const f16* __restrict__ qh,
                                                 const f16* __restrict__ kh,
                                                 const f16* __restrict__ vh,
                                                 float* __restrict__ att) {
    __shared__ __align__(16) f16 plds[4][32][72];  // per-wave P buffer, padded stride

    int t = threadIdx.x;
    int wave = t >> 6, lane = t & 63;
    int quad = lane >> 4, col = lane & 15;
    int bh = blockIdx.y;
    int i0 = blockIdx.x * 128 + wave * 32;

    const f16* qb = qh + (size_t)bh * NN * 32;
    const f16* kb = kh + (size_t)bh * NN * 32;
    const f16* vb = vh + (size_t)bh * 32 * NN;

    f16x8 qa[2];
#pragma unroll
    for (int rt = 0; rt < 2; rt++)
        qa[rt] = *(const f16x8*)(qb + (size_t)(i0 + rt * 16 + col) * 32 + quad * 8);

    f32x4 zf = {0.f, 0.f, 0.f, 0.f};
    f32x4 oacc[2][2];
    float lsum[2][4];
#pragma unroll
    for (int rt = 0; rt < 2; rt++) {
#pragma unroll
        for (int nc = 0; nc < 2; nc++) oacc[rt][nc] = zf;
#pragma unroll
        for (int r = 0; r < 4; r++) lsum[rt][r] = 0.f;
    }

    for (int j0 = 0; j0 < NN; j0 += 64) {
        // K B-frags: B[k=d][n=key] from kh[key][d] (contiguous 8 d per lane)
        f16x8 kf[4];
#pragma unroll
        for (int s = 0; s < 4; s++)
            kf[s] = *(const f16x8*)(kb + (size_t)(j0 + s * 16 + col) * 32 + quad * 8);
        // V B-frags: B[k=key][n=dh] from vh[d][i] (contiguous 8 keys per lane)
        f16x8 vf[2][2];
#pragma unroll
        for (int kc = 0; kc < 2; kc++)
#pragma unroll
            for (int nc = 0; nc < 2; nc++)
                vf[kc][nc] = *(const f16x8*)(vb + (size_t)(nc * 16 + col) * NN + j0 + kc * 32 + quad * 8);

        // S = Q K^T  (rows=q, cols=key)
        f32x4 sf[2][4];
#pragma unroll
        for (int rt = 0; rt < 2; rt++)
#pragma unroll
            for (int s = 0; s < 4; s++)
                sf[rt][s] = __builtin_amdgcn_mfma_f32_16x16x32_f16(qa[rt], kf[s], zf, 0, 0, 0);

        // p = exp(s - 10), accumulate per-lane partial row sums
        f16 ph[2][4][4];
#pragma unroll
        for (int rt = 0; rt < 2; rt++)
#pragma unroll
            for (int s = 0; s < 4; s++)
#pragma unroll
                for (int r = 0; r < 4; r++) {
                    float p = __expf(sf[rt][s][r] - EXPSHIFT);
                    lsum[rt][r] += p;
                    ph[rt][s][r] = (f16)p;
                }

        // write P to LDS [row][key], quad-rotated sub order (bank spread)
#pragma unroll
        for (int rt = 0; rt < 2; rt++)
#pragma unroll
            for (int s0 = 0; s0 < 4; s0++) {
                int ss = (s0 + quad) & 3;
#pragma unroll
                for (int r = 0; r < 4; r++)
                    plds[wave][rt * 16 + quad * 4 + r][ss * 16 + col] = ph[rt][ss][r];
            }

        // PV: A = P[16][64] (LDS), B = V frags; accumulate O
#pragma unroll
        for (int rt = 0; rt < 2; rt++)
#pragma unroll
            for (int kc = 0; kc < 2; kc++) {
                f16x8 pa = *(const f16x8*)&plds[wave][rt * 16 + col][kc * 32 + quad * 8];
#pragma unroll
                for (int nc = 0; nc < 2; nc++)
                    oacc[rt][nc] = __builtin_amdgcn_mfma_f32_16x16x32_f16(pa, vf[kc][nc], oacc[rt][nc], 0, 0, 0);
            }
    }

    // final row sums (16 lanes of each quad hold partials for rows quad*4+r)
#pragma unroll
    for (int rt = 0; rt < 2; rt++)
#pragma unroll
        for (int r = 0; r < 4; r++) {
#pragma unroll
            for (int m = 8; m >= 1; m >>= 1)
                lsum[rt][r] += __shfl_xor(lsum[rt][r], m);
        }

    // scale by 1/l, transpose via LDS, coalesced store att[bh*32+dh][i]
    float* tb = (float*)&plds[wave][0][0];  // 32x33 fp32 = 4224 B <= 4608 B
#pragma unroll
    for (int rt = 0; rt < 2; rt++) {
        float invl[4];
#pragma unroll
        for (int r = 0; r < 4; r++) invl[r] = __builtin_amdgcn_rcpf(lsum[rt][r]);
#pragma unroll
        for (int nc = 0; nc < 2; nc++)
#pragma unroll
            for (int r = 0; r < 4; r++)
                tb[(nc * 16 + col) * 33 + rt * 16 + quad * 4 + r] = oacc[rt][nc][r] * invl[r];
    }
#pragma unroll
    for (int s = 0; s < 16; s++) {
        int dh = s * 2 + (lane >> 5);
        int ii = lane & 31;
        att[((size_t)bh * 32 + dh) * NN + i0 + ii] = tb[dh * 33 + ii];
    }
}

// ---------------- kernel 4: output projection + bias ----------------
__global__ __launch_bounds__(256) void out_proj(const float* __restrict__ att,
                                                const float* __restrict__ wo,
                                                const float* __restrict__ bo,
                                                float* __restrict__ out) {
    int i = blockIdx.x * 256 + threadIdx.x;
    int o0 = blockIdx.y * 8;
    int b = blockIdx.z;
    const float* ab = att + (size_t)b * HID * NN;
    float acc[8];
#pragma unroll
    for (int oo = 0; oo < 8; oo++) acc[oo] = 0.f;
    for (int c = 0; c < HID; c++) {
        float av = ab[(size_t)c * NN + i];
#pragma unroll
        for (int oo = 0; oo < 8; oo++)
            acc[oo] = fmaf(wo[(o0 + oo) * HID + c], av, acc[oo]);
    }
#pragma unroll
    for (int oo = 0; oo < 8; oo++)
        out[((size_t)b * CC + o0 + oo) * NN + i] = acc[oo] + bo[o0 + oo];
}

extern "C" void kernel_launch(void* const* d_in, const int* in_sizes, int n_in,
                              void* d_out, int out_size, void* d_ws, size_t ws_size,
                              hipStream_t stream) {
    const float* x     = (const float*)d_in[0];
    const float* w_qkv = (const float*)d_in[1];
    const float* w_out = (const float*)d_in[2];
    const float* b_out = (const float*)d_in[3];
    float* out = (float*)d_out;

    const size_t SEG = (size_t)BB * HID * NN;  // 2,097,152 elements
    float* wsf = (float*)d_ws;
    float* q32 = wsf;            // 8 MB
    float* k32 = wsf + SEG;      // 8 MB
    f16* qh = (f16*)(wsf + 2 * SEG);  // 4 MB
    f16* kh = qh + SEG;               // 4 MB
    f16* vh = kh + SEG;               // 4 MB
    float* att = q32;  // alias: q32 is dead after l2norm_cvt

    qkv_proj<<<dim3(NN / 256, 384 / 8, BB), 256, 0, stream>>>(x, w_qkv, q32, k32, vh);
    l2norm_cvt<<<dim3(NN / 256, BB * NHEAD, 2), 256, 0, stream>>>(q32, k32, qh, kh);
    attn_mfma<<<dim3(NN / 128, BB * NHEAD), 256, 0, stream>>>(qh, kh, vh, att);
    out_proj<<<dim3(NN / 256, CC / 8, BB), 256, 0, stream>>>(att, w_out, b_out, out);
}

// Round 4
// 339.279 us; speedup vs baseline: 7.6317x; 2.0686x over previous
//
#include <hip/hip_runtime.h>
#include <math.h>

#define BB 4
#define CC 256
#define NHEAD 4
#define DH 32
#define NN 4096
#define HID 128

typedef _Float16 f16;
typedef _Float16 f16x8 __attribute__((ext_vector_type(8)));
typedef _Float16 f16x4 __attribute__((ext_vector_type(4)));
typedef float f32x4 __attribute__((ext_vector_type(4)));

// q-hat prescaled by 10*log2(e) so p = exp2(sT - 14.4269) = exp(10*(sim-1))
#define QPRESCALE 14.42695041f
#define NSHIFT 14.42695041f

#if __has_builtin(__builtin_amdgcn_exp2f)
#define EXP2F(x) __builtin_amdgcn_exp2f(x)
#else
#define EXP2F(x) __expf((x)*0.6931471805599453f)
#endif

// ---------------- kernel 1: qkv projection ----------------
__global__ __launch_bounds__(256) void qkv_proj(const float* __restrict__ x,
                                                const float* __restrict__ w,
                                                float* __restrict__ q32,
                                                float* __restrict__ k32,
                                                f16* __restrict__ vh) {
    int i = blockIdx.x * 256 + threadIdx.x;
    int o0 = blockIdx.y * 8;
    int b = blockIdx.z;
    const float* xb = x + (size_t)b * CC * NN;
    float acc[8];
#pragma unroll
    for (int oo = 0; oo < 8; oo++) acc[oo] = 0.f;
    for (int c = 0; c < CC; c++) {
        float xv = xb[(size_t)c * NN + i];
#pragma unroll
        for (int oo = 0; oo < 8; oo++)
            acc[oo] = fmaf(w[(o0 + oo) * CC + c], xv, acc[oo]);
    }
#pragma unroll
    for (int oo = 0; oo < 8; oo++) {
        int o = o0 + oo;
        if (o < 128) {
            q32[((size_t)b * 128 + o) * NN + i] = acc[oo];
        } else if (o < 256) {
            k32[((size_t)b * 128 + (o - 128)) * NN + i] = acc[oo];
        } else {
            vh[((size_t)b * 128 + (o - 256)) * NN + i] = (f16)acc[oo];
        }
    }
}

// ---------------- kernel 2: l2 normalize + f16 transpose to i-major ----------
__global__ __launch_bounds__(256) void l2norm_cvt(const float* __restrict__ q32,
                                                  const float* __restrict__ k32,
                                                  f16* __restrict__ qh,
                                                  f16* __restrict__ kh) {
    int i = blockIdx.x * 256 + threadIdx.x;
    int bh = blockIdx.y;
    const float* src = (blockIdx.z == 0) ? q32 : k32;
    f16* dst = (blockIdx.z == 0) ? qh : kh;
    float extra = (blockIdx.z == 0) ? QPRESCALE : 1.0f;
    float v[32];
    float ss = 0.f;
#pragma unroll
    for (int d = 0; d < 32; d++) {
        v[d] = src[((size_t)bh * 32 + d) * NN + i];
        ss = fmaf(v[d], v[d], ss);
    }
    float inv = extra / fmaxf(sqrtf(ss), 1e-12f);
    f16x8 o[4];
#pragma unroll
    for (int g = 0; g < 4; g++)
#pragma unroll
        for (int e = 0; e < 8; e++) o[g][e] = (f16)(v[g * 8 + e] * inv);
    f16x8* dp = (f16x8*)(dst + ((size_t)bh * NN + i) * 32);
#pragma unroll
    for (int g = 0; g < 4; g++) dp[g] = o[g];
}

// ---------------- kernel 3: MFMA flash attention, S^T trick ----------------
// Wave owns 32 q rows. S^T = K·Q^T so the 16x16 C layout (q=lane&15,
// key=quad*4+reg) IS the A-layout of mfma 16x16x16 f16 for PV: no LDS, no
// cross-lane movement, no dynamic indexing. K/V double-buffered in registers.
struct KV32 {
    f16x8 k0, k1;           // K A-frags, key subtiles [0,16) and [16,32)
    f16x4 v0n0, v0n1;       // V B-frags, keys [0,16): dh [0,16), [16,32)
    f16x4 v1n0, v1n1;       // V B-frags, keys [16,32)
};

__device__ __forceinline__ KV32 load_kv(const f16* __restrict__ kb,
                                        const f16* __restrict__ vb,
                                        int jb, int col, int quad) {
    KV32 f;
    f.k0 = *(const f16x8*)(kb + (size_t)(jb + col) * 32 + quad * 8);
    f.k1 = *(const f16x8*)(kb + (size_t)(jb + 16 + col) * 32 + quad * 8);
    f.v0n0 = *(const f16x4*)(vb + (size_t)col * NN + jb + quad * 4);
    f.v0n1 = *(const f16x4*)(vb + (size_t)(16 + col) * NN + jb + quad * 4);
    f.v1n0 = *(const f16x4*)(vb + (size_t)col * NN + jb + 16 + quad * 4);
    f.v1n1 = *(const f16x4*)(vb + (size_t)(16 + col) * NN + jb + 16 + quad * 4);
    return f;
}

__device__ __forceinline__ f16x4 expblk(f32x4 s, float& lacc) {
    f16x4 r;
#pragma unroll
    for (int i = 0; i < 4; i++) {
        float p = EXP2F(s[i] - NSHIFT);
        lacc += p;
        r[i] = (f16)p;
    }
    return r;
}

__device__ __forceinline__ void compute32(const KV32& f, f16x8 qB0, f16x8 qB1,
                                          f32x4& o00, f32x4& o01,
                                          f32x4& o10, f32x4& o11,
                                          float& l0, float& l1) {
    const f32x4 z = {0.f, 0.f, 0.f, 0.f};
    // S^T tiles: rows=key, cols=q
    f32x4 s00 = __builtin_amdgcn_mfma_f32_16x16x32_f16(f.k0, qB0, z, 0, 0, 0);
    f32x4 s10 = __builtin_amdgcn_mfma_f32_16x16x32_f16(f.k0, qB1, z, 0, 0, 0);
    f32x4 s01 = __builtin_amdgcn_mfma_f32_16x16x32_f16(f.k1, qB0, z, 0, 0, 0);
    f32x4 s11 = __builtin_amdgcn_mfma_f32_16x16x32_f16(f.k1, qB1, z, 0, 0, 0);
    f16x4 p00 = expblk(s00, l0);  // (keysub0, rt0)
    f16x4 p10 = expblk(s10, l1);  // (keysub0, rt1)
    f16x4 p01 = expblk(s01, l0);  // (keysub1, rt0)
    f16x4 p11 = expblk(s11, l1);  // (keysub1, rt1)
    // PV: A=P (m=q,k=key) direct from regs; B=V (k=key,n=dh)
    o00 = __builtin_amdgcn_mfma_f32_16x16x16f16(p00, f.v0n0, o00, 0, 0, 0);
    o01 = __builtin_amdgcn_mfma_f32_16x16x16f16(p00, f.v0n1, o01, 0, 0, 0);
    o10 = __builtin_amdgcn_mfma_f32_16x16x16f16(p10, f.v0n0, o10, 0, 0, 0);
    o11 = __builtin_amdgcn_mfma_f32_16x16x16f16(p10, f.v0n1, o11, 0, 0, 0);
    o00 = __builtin_amdgcn_mfma_f32_16x16x16f16(p01, f.v1n0, o00, 0, 0, 0);
    o01 = __builtin_amdgcn_mfma_f32_16x16x16f16(p01, f.v1n1, o01, 0, 0, 0);
    o10 = __builtin_amdgcn_mfma_f32_16x16x16f16(p11, f.v1n0, o10, 0, 0, 0);
    o11 = __builtin_amdgcn_mfma_f32_16x16x16f16(p11, f.v1n1, o11, 0, 0, 0);
}

__global__ __launch_bounds__(256) void attn_mfma(const f16* __restrict__ qh,
                                                 const f16* __restrict__ kh,
                                                 const f16* __restrict__ vh,
                                                 float* __restrict__ att) {
    __shared__ float tb[4][32][33];
    int t = threadIdx.x;
    int wave = t >> 6, lane = t & 63;
    int quad = lane >> 4, col = lane & 15;
    int bh = blockIdx.y;
    int i0 = blockIdx.x * 128 + wave * 32;

    const f16* qb = qh + (size_t)bh * NN * 32;
    const f16* kb = kh + (size_t)bh * NN * 32;
    const f16* vb = vh + (size_t)bh * 32 * NN;

    f16x8 qB0 = *(const f16x8*)(qb + (size_t)(i0 + col) * 32 + quad * 8);
    f16x8 qB1 = *(const f16x8*)(qb + (size_t)(i0 + 16 + col) * 32 + quad * 8);

    f32x4 o00 = {0.f, 0.f, 0.f, 0.f}, o01 = o00, o10 = o00, o11 = o00;
    float l0 = 0.f, l1 = 0.f;

    KV32 c0 = load_kv(kb, vb, 0, col, quad);
    for (int j0 = 0; j0 < NN; j0 += 64) {
        KV32 c1 = load_kv(kb, vb, j0 + 32, col, quad);
        compute32(c0, qB0, qB1, o00, o01, o10, o11, l0, l1);
        if (j0 + 64 < NN) c0 = load_kv(kb, vb, j0 + 64, col, quad);
        compute32(c1, qB0, qB1, o00, o01, o10, o11, l0, l1);
    }

    // row sums: lane already owns q=col; reduce across quads
    l0 += __shfl_xor(l0, 16); l0 += __shfl_xor(l0, 32);
    l1 += __shfl_xor(l1, 16); l1 += __shfl_xor(l1, 32);

#pragma unroll
    for (int r = 0; r < 4; r++) {
        float i0v = __builtin_amdgcn_rcpf(__shfl(l0, quad * 4 + r));
        float i1v = __builtin_amdgcn_rcpf(__shfl(l1, quad * 4 + r));
        tb[wave][quad * 4 + r][col] = o00[r] * i0v;
        tb[wave][quad * 4 + r][16 + col] = o01[r] * i0v;
        tb[wave][16 + quad * 4 + r][col] = o10[r] * i1v;
        tb[wave][16 + quad * 4 + r][16 + col] = o11[r] * i1v;
    }
    __syncthreads();
#pragma unroll
    for (int it = 0; it < 16; it++) {
        int dh = it * 2 + (lane >> 5);
        int ii = lane & 31;
        att[((size_t)bh * 32 + dh) * NN + i0 + ii] = tb[wave][ii][dh];
    }
}

// ---------------- kernel 4: output projection + bias ----------------
__global__ __launch_bounds__(256) void out_proj(const float* __restrict__ att,
                                                const float* __restrict__ wo,
                                                const float* __restrict__ bo,
                                                float* __restrict__ out) {
    int i = blockIdx.x * 256 + threadIdx.x;
    int o0 = blockIdx.y * 8;
    int b = blockIdx.z;
    const float* ab = att + (size_t)b * HID * NN;
    float acc[8];
#pragma unroll
    for (int oo = 0; oo < 8; oo++) acc[oo] = 0.f;
    for (int c = 0; c < HID; c++) {
        float av = ab[(size_t)c * NN + i];
#pragma unroll
        for (int oo = 0; oo < 8; oo++)
            acc[oo] = fmaf(wo[(o0 + oo) * HID + c], av, acc[oo]);
    }
#pragma unroll
    for (int oo = 0; oo < 8; oo++)
        out[((size_t)b * CC + o0 + oo) * NN + i] = acc[oo] + bo[o0 + oo];
}

extern "C" void kernel_launch(void* const* d_in, const int* in_sizes, int n_in,
                              void* d_out, int out_size, void* d_ws, size_t ws_size,
                              hipStream_t stream) {
    const float* x     = (const float*)d_in[0];
    const float* w_qkv = (const float*)d_in[1];
    const float* w_out = (const float*)d_in[2];
    const float* b_out = (const float*)d_in[3];
    float* out = (float*)d_out;

    const size_t SEG = (size_t)BB * HID * NN;  // 2,097,152 elements
    float* wsf = (float*)d_ws;
    float* q32 = wsf;                 // 8 MB
    float* k32 = wsf + SEG;           // 8 MB
    f16* qh = (f16*)(wsf + 2 * SEG);  // 4 MB
    f16* kh = qh + SEG;               // 4 MB
    f16* vh = kh + SEG;               // 4 MB
    float* att = q32;                 // q32 dead after l2norm_cvt

    qkv_proj<<<dim3(NN / 256, 384 / 8, BB), 256, 0, stream>>>(x, w_qkv, q32, k32, vh);
    l2norm_cvt<<<dim3(NN / 256, BB * NHEAD, 2), 256, 0, stream>>>(q32, k32, qh, kh);
    attn_mfma<<<dim3(NN / 128, BB * NHEAD), 256, 0, stream>>>(qh, kh, vh, att);
    out_proj<<<dim3(NN / 256, CC / 8, BB), 256, 0, stream>>>(att, w_out, b_out, out);
}